// Round 1
// 473.074 us; speedup vs baseline: 1.3250x; 1.3250x over previous
//
#include <hip/hip_runtime.h>
#include <cstddef>

// ---------------------------------------------------------------------------
// HGTConv, algebraically reduced:
//   softmax(scores).mean(-1) == 1/8 exactly  =>  attention path is dead code.
//   out = relu( mx @ (Wv@Wm@Wout)/8 + beta*((bv@Wm+bm)@Wout)/8 + bout + x )
//   with mx = segsum(x[src])/max(cnt,1), beta = (cnt>0).
//
// R3 (this round): agg_gemm was latency-bound (Occ 26% = 2 waves/SIMD from
// ~132 unified regs; 1-deep serial gather chain). Changes:
//   - 32-row blocks, per-wave tile 32x64 (acc[2][4] = 32 regs) +
//     __launch_bounds__(256,4) => 4 waves/SIMD.
//   - 8-row interleaved gather per wave => 8 independent load chains.
//   - both passes in ONE launch (game blocks first), CSR/weight tail fused
//     14 launches + 2 memcpys -> 5 launches (cursor written by scan_add).
// ---------------------------------------------------------------------------

#define DD 256
#define SCAN_CHUNK 2048

typedef __attribute__((ext_vector_type(8))) short short8;
typedef __attribute__((ext_vector_type(4))) float floatx4;

__device__ __forceinline__ short f2bf(float f) {
    union { float f; unsigned u; } c;
    c.f = f;
    unsigned r = c.u + 0x7fffu + ((c.u >> 16) & 1u);
    return (short)(r >> 16);
}

// ---- fused launch A: weight GEMM stage 1 (T = Wv@Wm, x2) + both histograms
__global__ __launch_bounds__(256) void fuseA(const float* __restrict__ A0,
                                             const float* __restrict__ B0,
                                             float* __restrict__ C0,
                                             const float* __restrict__ A1,
                                             const float* __restrict__ B1,
                                             float* __restrict__ C1,
                                             const int* __restrict__ dst0,
                                             int* __restrict__ cnt0, int E0,
                                             const int* __restrict__ dst1,
                                             int* __restrict__ cnt1, int E1) {
    __shared__ float As[DD];
    const int bid = blockIdx.x;
    const int c = threadIdx.x;
    if (bid < 512) {
        const int which = bid >> 8;
        const int r = bid & 255;
        const float* A = which ? A1 : A0;
        const float* B = which ? B1 : B0;
        float* C = which ? C1 : C0;
        As[c] = A[r * DD + c];
        __syncthreads();
        float acc = 0.f;
#pragma unroll 8
        for (int k = 0; k < DD; ++k) acc += As[k] * B[k * DD + c];
        C[r * DD + c] = acc;
    } else {
        const int nb0 = (E0 + 255) >> 8;
        const int b = bid - 512;
        if (b < nb0) {
            const int i = b * 256 + c;
            if (i < E0) atomicAdd(&cnt0[dst0[i]], 1);
        } else {
            const int i = (b - nb0) * 256 + c;
            if (i < E1) atomicAdd(&cnt1[dst1[i]], 1);
        }
    }
}

// ---- fused launch B: Wf = T@Wout*0.125 -> swizzled bf16 (x2) + scan_chunk(x2)
// Bsw layout: Bsw[((k>>5)*16 + (n>>4))*64 + ((n&15)|(((k>>3)&3)<<4))][k&7]
__global__ __launch_bounds__(256) void fuseB(const float* __restrict__ A0,
                                             const float* __restrict__ B0,
                                             short* __restrict__ C0,
                                             const float* __restrict__ A1,
                                             const float* __restrict__ B1,
                                             short* __restrict__ C1,
                                             int* __restrict__ off_g,
                                             int* __restrict__ sums_g, int n_g,
                                             int* __restrict__ off_u,
                                             int* __restrict__ sums_u, int n_u) {
    __shared__ float As[DD];
    __shared__ int ls[256];
    const int bid = blockIdx.x;
    const int tid = threadIdx.x;
    if (bid < 512) {
        const int which = bid >> 8;
        const int r = bid & 255;  // k index of Wf
        const int c = tid;        // n index of Wf
        const float* A = which ? A1 : A0;
        const float* B = which ? B1 : B0;
        short* C = which ? C1 : C0;
        As[c] = A[r * DD + c];
        __syncthreads();
        float acc = 0.f;
#pragma unroll 8
        for (int k = 0; k < DD; ++k) acc += As[k] * B[k * DD + c];
        const int idx = ((((r >> 5) * 16 + (c >> 4)) * 64 +
                          ((c & 15) | (((r >> 3) & 3) << 4))) << 3) + (r & 7);
        C[idx] = f2bf(acc * 0.125f);
    } else {
        const int nch_g = (n_g + SCAN_CHUNK - 1) / SCAN_CHUNK;
        const int b = bid - 512;
        int* off;
        int* sums;
        int n, cb;
        if (b < nch_g) { off = off_g; sums = sums_g; n = n_g; cb = b; }
        else { off = off_u; sums = sums_u; n = n_u; cb = b - nch_g; }
        const int base = cb * SCAN_CHUNK + tid * 8;
        int v[8];
        int s = 0;
#pragma unroll
        for (int i = 0; i < 8; ++i) {
            const int idx = base + i;
            v[i] = (idx < n) ? off[idx] : 0;
            s += v[i];
        }
        ls[tid] = s;
        __syncthreads();
        for (int d = 1; d < 256; d <<= 1) {
            const int t = (tid >= d) ? ls[tid - d] : 0;
            __syncthreads();
            ls[tid] += t;
            __syncthreads();
        }
        int excl = tid ? ls[tid - 1] : 0;
        if (tid == 255) sums[cb] = ls[255];
#pragma unroll
        for (int i = 0; i < 8; ++i) {
            const int idx = base + i;
            if (idx < n) off[idx] = excl;
            excl += v[i];
        }
    }
}

// ---- fused launch C: bias fusion (2 blocks) + scan_sums (2 blocks)
__global__ __launch_bounds__(256) void fuseC(const float* __restrict__ bv0,
                                             const float* __restrict__ Wm0,
                                             const float* __restrict__ bm0,
                                             const float* __restrict__ Wout0,
                                             float* __restrict__ bb0,
                                             const float* __restrict__ bv1,
                                             const float* __restrict__ Wm1,
                                             const float* __restrict__ bm1,
                                             const float* __restrict__ Wout1,
                                             float* __restrict__ bb1,
                                             int* __restrict__ sums_g, int nch_g,
                                             int* __restrict__ sums_u, int nch_u) {
    __shared__ float t[DD];
    __shared__ int ls[256];
    const int tid = threadIdx.x;
    if (blockIdx.x < 2) {
        const int w = blockIdx.x;
        const float* bv = w ? bv1 : bv0;
        const float* Wm = w ? Wm1 : Wm0;
        const float* bm = w ? bm1 : bm0;
        const float* Wout = w ? Wout1 : Wout0;
        float* bb = w ? bb1 : bb0;
        float acc = bm[tid];
#pragma unroll 8
        for (int k = 0; k < DD; ++k) acc += bv[k] * Wm[k * DD + tid];
        t[tid] = acc;
        __syncthreads();
        float acc2 = 0.f;
#pragma unroll 8
        for (int k = 0; k < DD; ++k) acc2 += t[k] * Wout[k * DD + tid];
        bb[tid] = acc2 * 0.125f;
    } else {
        int* sums = (blockIdx.x == 2) ? sums_g : sums_u;
        const int nch = (blockIdx.x == 2) ? nch_g : nch_u;
        ls[tid] = (tid < nch) ? sums[tid] : 0;
        __syncthreads();
        for (int d = 1; d < 256; d <<= 1) {
            const int t2 = (tid >= d) ? ls[tid - d] : 0;
            __syncthreads();
            ls[tid] += t2;
            __syncthreads();
        }
        if (tid < nch) sums[tid] = tid ? ls[tid - 1] : 0;
    }
}

// ---- fused launch D: scan_add(x2) + cursor init (replaces 2 memcpys)
__global__ __launch_bounds__(256) void fuseD(int* __restrict__ off_g,
                                             const int* __restrict__ sums_g,
                                             int* __restrict__ cur_g, int n_g, int Eg,
                                             int* __restrict__ off_u,
                                             const int* __restrict__ sums_u,
                                             int* __restrict__ cur_u, int n_u, int Eu) {
    const int gidx = blockIdx.x * 256 + threadIdx.x;
    const int span_g = n_g + 1;
    if (gidx < span_g) {
        if (gidx < n_g) {
            const int v = off_g[gidx] + sums_g[gidx / SCAN_CHUNK];
            off_g[gidx] = v;
            cur_g[gidx] = v;
        } else {
            off_g[n_g] = Eg;
        }
    } else {
        const int idx = gidx - span_g;
        if (idx < n_u) {
            const int v = off_u[idx] + sums_u[idx / SCAN_CHUNK];
            off_u[idx] = v;
            cur_u[idx] = v;
        } else if (idx == n_u) {
            off_u[n_u] = Eu;
        }
    }
}

// ---- fused launch E: permute (x2)
__global__ __launch_bounds__(256) void fuseE(const int* __restrict__ src0,
                                             const int* __restrict__ dst0,
                                             int* __restrict__ cur0,
                                             int* __restrict__ perm0, int E0,
                                             const int* __restrict__ src1,
                                             const int* __restrict__ dst1,
                                             int* __restrict__ cur1,
                                             int* __restrict__ perm1, int E1) {
    const int nb0 = (E0 + 255) >> 8;
    const int b = blockIdx.x;
    const int tid = threadIdx.x;
    if (b < nb0) {
        const int i = b * 256 + tid;
        if (i < E0) {
            const int pos = atomicAdd(&cur0[dst0[i]], 1);
            perm0[pos] = src0[i];
        }
    } else {
        const int i = (b - nb0) * 256 + tid;
        if (i < E1) {
            const int pos = atomicAdd(&cur1[dst1[i]], 1);
            perm1[pos] = src1[i];
        }
    }
}

// ---- fused aggregate + bf16-MFMA GEMM + epilogue, BOTH passes in one grid --
// Block = 32 dst rows, 256 threads (4 waves).
// Phase 1: each wave owns 8 rows; edges round-robined across the 8 rows so
//          8 independent perm->row load chains are in flight (MLP=8).
// Phase 2: wave w computes rows[0:32) x cols[w*64, w*64+64) with
//          v_mfma_f32_16x16x32_bf16; acc[2][4] keeps regs ~100 so
//          __launch_bounds__(256,4) holds 4 waves/SIMD.
__global__ __launch_bounds__(256, 4) void agg_gemm2(
    const float* __restrict__ x_user, const float* __restrict__ x_game,
    const int* __restrict__ perm_rev, const int* __restrict__ off_user,
    const short* __restrict__ Bsw_rev, const float* __restrict__ bb_rev,
    const float* __restrict__ bout_user,
    const int* __restrict__ perm_played, const int* __restrict__ off_game,
    const short* __restrict__ Bsw_played, const float* __restrict__ bb_played,
    const float* __restrict__ bout_game,
    float* __restrict__ outp, int n_user, int n_game, int nb_game) {
    __shared__ short As[32][264];  // +8 pad (same geometry as prior kernel)
    __shared__ float bt[32];

    const int tid = threadIdx.x;
    const int wave = __builtin_amdgcn_readfirstlane(tid >> 6);
    const int lane = tid & 63;

    const float* x_src;
    const float* x_res;
    const int* perm;
    const int* off;
    const short* Bsw;
    const float* bb;
    const float* bout;
    float* out;
    int M, r0;
    if ((int)blockIdx.x < nb_game) {
        // game pass first: deeper degrees -> longer blocks scheduled early
        x_src = x_user; x_res = x_game;
        perm = perm_played; off = off_game;
        Bsw = Bsw_played; bb = bb_played; bout = bout_game;
        out = outp + (size_t)n_user * DD;
        M = n_game;
        r0 = (int)blockIdx.x * 32;
    } else {
        x_src = x_game; x_res = x_user;
        perm = perm_rev; off = off_user;
        Bsw = Bsw_rev; bb = bb_rev; bout = bout_user;
        out = outp;
        M = n_user;
        r0 = ((int)blockIdx.x - nb_game) * 32;
    }

    // ---- phase 1: interleaved gather, 8 rows per wave, 8 chains in flight
    int e[8], en[8], deg[8];
    float4 acc[8];
#pragma unroll
    for (int j = 0; j < 8; ++j) {
        const int r = r0 + wave * 8 + j;
        e[j] = (r < M) ? off[r] : 0;
        en[j] = (r < M) ? off[r + 1] : 0;
        deg[j] = en[j] - e[j];
        acc[j].x = 0.f; acc[j].y = 0.f; acc[j].z = 0.f; acc[j].w = 0.f;
    }
    int mdeg = 0;
#pragma unroll
    for (int j = 0; j < 8; ++j) mdeg = max(mdeg, deg[j]);
    for (int t = 0; t < mdeg; ++t) {
        float4 v[8];
        bool h[8];
#pragma unroll
        for (int j = 0; j < 8; ++j) {
            h[j] = e[j] < en[j];
            if (h[j]) {
                const int s = perm[e[j]++];
                v[j] = ((const float4*)(x_src + (size_t)s * DD))[lane];
            }
        }
#pragma unroll
        for (int j = 0; j < 8; ++j) {
            if (h[j]) {
                acc[j].x += v[j].x;
                acc[j].y += v[j].y;
                acc[j].z += v[j].z;
                acc[j].w += v[j].w;
            }
        }
    }
#pragma unroll
    for (int j = 0; j < 8; ++j) {
        const int lr = wave * 8 + j;
        const float inv = 1.0f / fmaxf((float)deg[j], 1.0f);
        short4 b4;
        b4.x = f2bf(acc[j].x * inv);
        b4.y = f2bf(acc[j].y * inv);
        b4.z = f2bf(acc[j].z * inv);
        b4.w = f2bf(acc[j].w * inv);
        *(short4*)&As[lr][lane * 4] = b4;
        if (lane == 0) bt[lr] = (deg[j] > 0) ? 1.0f : 0.0f;
    }
    __syncthreads();

    // ---- phase 2: MFMA, 32 rows x 64 cols per wave ----
    const int quad = lane >> 4;
    const int l16 = lane & 15;
    floatx4 cacc[2][4];
#pragma unroll
    for (int rt = 0; rt < 2; ++rt)
#pragma unroll
        for (int ct = 0; ct < 4; ++ct) cacc[rt][ct] = (floatx4){0.f, 0.f, 0.f, 0.f};

    for (int kb8 = 0; kb8 < 8; ++kb8) {
        short8 af[2];
#pragma unroll
        for (int rt = 0; rt < 2; ++rt)
            af[rt] = *(const short8*)&As[rt * 16 + l16][kb8 * 32 + quad * 8];
        short8 bf[4];
        const short* bp = Bsw + (((size_t)(kb8 * 16 + wave * 4) * 64 + lane) << 3);
#pragma unroll
        for (int ct = 0; ct < 4; ++ct)
            bf[ct] = *(const short8*)(bp + (ct << 9));
#pragma unroll
        for (int rt = 0; rt < 2; ++rt)
#pragma unroll
            for (int ct = 0; ct < 4; ++ct)
                cacc[rt][ct] = __builtin_amdgcn_mfma_f32_16x16x32_bf16(
                    af[rt], bf[ct], cacc[rt][ct], 0, 0, 0);
    }

    // ---- epilogue ----
    float bbv[4], bov[4];
#pragma unroll
    for (int ct = 0; ct < 4; ++ct) {
        const int n = wave * 64 + ct * 16 + l16;
        bbv[ct] = bb[n];
        bov[ct] = bout[n];
    }
#pragma unroll
    for (int rt = 0; rt < 2; ++rt) {
#pragma unroll
        for (int j = 0; j < 4; ++j) {
            const int lr = rt * 16 + quad * 4 + j;
            const int r = r0 + lr;
            if (r < M) {
                const float btv = bt[lr];
                const float* xr = x_res + (size_t)r * DD;
                float* orow = out + (size_t)r * DD;
#pragma unroll
                for (int ct = 0; ct < 4; ++ct) {
                    const int n = wave * 64 + ct * 16 + l16;
                    const float o = cacc[rt][ct][j] + btv * bbv[ct] + bov[ct] + xr[n];
                    orow[n] = fmaxf(o, 0.f);
                }
            }
        }
    }
}

extern "C" void kernel_launch(void* const* d_in, const int* in_sizes, int n_in,
                              void* d_out, int out_size, void* d_ws, size_t ws_size,
                              hipStream_t stream) {
    const float* x_user = (const float*)d_in[0];
    const float* x_game = (const float*)d_in[1];
    const float* Wv_user = (const float*)d_in[6];
    const float* bv_user = (const float*)d_in[7];
    const float* Wout_user = (const float*)d_in[8];
    const float* bout_user = (const float*)d_in[9];
    const float* Wv_game = (const float*)d_in[14];
    const float* bv_game = (const float*)d_in[15];
    const float* Wout_game = (const float*)d_in[16];
    const float* bout_game = (const float*)d_in[17];
    const float* Wm_played = (const float*)d_in[20];
    const float* bm_played = (const float*)d_in[21];
    const float* Wm_rev = (const float*)d_in[24];
    const float* bm_rev = (const float*)d_in[25];
    const int* ei_played_src = (const int*)d_in[26];
    const int* ei_played_dst = (const int*)d_in[27];
    const int* ei_rev_src = (const int*)d_in[28];
    const int* ei_rev_dst = (const int*)d_in[29];

    const int n_user = in_sizes[0] / DD;
    const int n_game = in_sizes[1] / DD;
    const int e_played = in_sizes[26];
    const int e_rev = in_sizes[28];

    float* out = (float*)d_out;

    // ---- workspace layout (unchanged) ----
    float* fws = (float*)d_ws;
    float* T0 = fws;                       // 64K f32
    float* T1 = T0 + DD * DD;              // 64K f32
    float* bb_played = T1 + DD * DD;       // 256
    float* bb_rev = bb_played + DD;        // 256
    short* Bsw_played = (short*)(bb_rev + DD);   // 64K bf16
    short* Bsw_rev = Bsw_played + DD * DD;       // 64K bf16
    int* iws = (int*)(Bsw_rev + DD * DD);
    int* off_game = iws;                      // n_game+1
    int* off_user = off_game + (n_game + 1);  // n_user+1
    int* cursor_game = off_user + (n_user + 1);
    int* cursor_user = cursor_game + n_game;
    int* sums_game = cursor_user + n_user;    // 256
    int* sums_user = sums_game + 256;         // 256
    int* perm_played = sums_user + 256;       // E
    int* perm_rev = perm_played + e_played;   // E
    (void)ws_size; (void)n_in; (void)out_size;

    // ---- zero histograms (off_game & off_user contiguous) ----
    hipMemsetAsync(off_game, 0, (size_t)(n_game + n_user + 2) * sizeof(int), stream);

    const int nbh_p = (e_played + 255) / 256;
    const int nbh_r = (e_rev + 255) / 256;
    const int nch_g = (n_game + SCAN_CHUNK - 1) / SCAN_CHUNK;
    const int nch_u = (n_user + SCAN_CHUNK - 1) / SCAN_CHUNK;

    // A: weight GEMM stage1 + histograms
    fuseA<<<512 + nbh_p + nbh_r, 256, 0, stream>>>(
        Wv_user, Wm_played, T0, Wv_game, Wm_rev, T1,
        ei_played_dst, off_game, e_played, ei_rev_dst, off_user, e_rev);
    // B: weight GEMM stage2 (swizzled bf16) + chunk scans
    fuseB<<<512 + nch_g + nch_u, 256, 0, stream>>>(
        T0, Wout_game, Bsw_played, T1, Wout_user, Bsw_rev,
        off_game, sums_game, n_game, off_user, sums_user, n_user);
    // C: bias fusion + chunk-sum scans
    fuseC<<<4, 256, 0, stream>>>(
        bv_user, Wm_played, bm_played, Wout_game, bb_played,
        bv_game, Wm_rev, bm_rev, Wout_user, bb_rev,
        sums_game, nch_g, sums_user, nch_u);
    // D: scan finalize + cursor init (no memcpys)
    const int ntot = (n_game + 1) + (n_user + 1);
    fuseD<<<(ntot + 255) / 256, 256, 0, stream>>>(
        off_game, sums_game, cursor_game, n_game, e_played,
        off_user, sums_user, cursor_user, n_user, e_rev);
    // E: permute both edge lists
    fuseE<<<nbh_p + nbh_r, 256, 0, stream>>>(
        ei_played_src, ei_played_dst, cursor_game, perm_played, e_played,
        ei_rev_src, ei_rev_dst, cursor_user, perm_rev, e_rev);

    // ---- fused aggregate + GEMM + epilogue, both passes in one grid ----
    const int nb_game = (n_game + 31) / 32;
    const int nb_user = (n_user + 31) / 32;
    agg_gemm2<<<nb_game + nb_user, 256, 0, stream>>>(
        x_user, x_game, perm_rev, off_user, Bsw_rev, bb_rev, bout_user,
        perm_played, off_game, Bsw_played, bb_played, bout_game,
        out, n_user, n_game, nb_game);
}